// Round 1
// baseline (752.560 us; speedup 1.0000x reference)
//
#include <hip/hip_runtime.h>

#define NN 50000
#define NE 1600000

// ---------------- CSR build ----------------

__global__ __launch_bounds__(256) void count_kernel(const int* __restrict__ dst,
                                                    int* __restrict__ cnt, int E) {
  int e = blockIdx.x * 256 + threadIdx.x;
  if (e < E) atomicAdd(&cnt[dst[e]], 1);
}

// single-block scan: reads counts from cnt, writes offs[0..n] (inclusive shifted)
// and rewrites cnt[i] = exclusive prefix (cursor for fill).
__global__ __launch_bounds__(1024) void scan_kernel(int* __restrict__ cnt,
                                                    int* __restrict__ offs, int n) {
  __shared__ int wsum[16];
  __shared__ int carry_s;
  int tid = threadIdx.x;
  int lane = tid & 63, wid = tid >> 6;
  if (tid == 0) { carry_s = 0; offs[0] = 0; }
  __syncthreads();
  for (int base = 0; base < n; base += 1024) {
    int i = base + tid;
    int v = (i < n) ? cnt[i] : 0;
    int x = v;
#pragma unroll
    for (int d = 1; d < 64; d <<= 1) {
      int y = __shfl_up(x, d, 64);
      if (lane >= d) x += y;
    }
    if (lane == 63) wsum[wid] = x;
    __syncthreads();
    if (tid < 16) {
      int s = wsum[tid];
#pragma unroll
      for (int d = 1; d < 16; d <<= 1) {
        int y = __shfl_up(s, d, 16);
        if (tid >= d) s += y;
      }
      wsum[tid] = s;
    }
    __syncthreads();
    int wave_off = (wid > 0) ? wsum[wid - 1] : 0;
    int c = carry_s;
    int incl = c + wave_off + x;
    if (i < n) {
      offs[i + 1] = incl;
      cnt[i] = incl - v;  // exclusive prefix -> cursor
    }
    __syncthreads();               // everyone read carry_s before update
    if (tid == 1023) carry_s = incl;
    __syncthreads();
  }
}

__global__ __launch_bounds__(256) void fill_kernel(const int* __restrict__ src,
                                                   const int* __restrict__ dst,
                                                   int* __restrict__ cur,
                                                   int* __restrict__ csr, int E) {
  int e = blockIdx.x * 256 + threadIdx.x;
  if (e < E) {
    int p = atomicAdd(&cur[dst[e]], 1);
    csr[p] = src[e];
  }
}

// ---------------- segment mean (gather form, no float atomics) ----------------

__global__ __launch_bounds__(128) void agg_kernel(const float* __restrict__ X,
                                                  const int* __restrict__ csr,
                                                  const int* __restrict__ offs,
                                                  float* __restrict__ out) {
  int n = blockIdx.x;
  int d = threadIdx.x;  // 128 threads = feature dim
  int s = offs[n], e = offs[n + 1];
  float acc = 0.0f;
  for (int j = s; j < e; ++j) {
    int sn = csr[j];
    acc += X[sn * 128 + d];
  }
  float deg = (float)(e - s);
  out[n * 128 + d] = acc / fmaxf(deg, 1.0f);
}

// ---------------- fused dual-GEMM: Out = act(Aself*Ws + Aneigh*Wn + b) ----------------
// block = 256 threads, 32 rows x 128 cols per block, K tiled by 32.
// In-place safe when Out aliases Aneigh (one block owns its 32-row stripe,
// all reads of those rows precede the epilogue writes; no column tiling).

__global__ __launch_bounds__(256) void gemm_sage(
    const float* __restrict__ As_g, const float* __restrict__ An_g,
    const float* __restrict__ Ws_g, const float* __restrict__ Wn_g,
    const float* __restrict__ bias, float* __restrict__ Out,
    int N, int relu) {
  __shared__ float As[32][36];   // transposed A tile [k][r], +4 pad (16B-aligned rows)
  __shared__ float An[32][36];
  __shared__ float Ws[32][128];
  __shared__ float Wn[32][128];
  int tid = threadIdx.x;
  int r0 = (tid >> 5) << 2;      // 8 row-groups * 4
  int c0 = (tid & 31) << 2;      // 32 col-groups * 4
  int rowBase = blockIdx.x * 32;

  float acc[4][4] = {{0.f}};

  int sr = tid >> 3;             // stage: A row 0..31
  int sk = (tid & 7) << 2;       // stage: A k-offset 0,4..28
  int grow = rowBase + sr;
  if (grow >= N) grow = N - 1;   // clamp stays inside this block's stripe
  int wc = (tid & 31) << 2;      // stage: W col*4
  int wk = tid >> 5;             // stage: W k-row 0..7

  for (int kb = 0; kb < 128; kb += 32) {
    float4 a4 = *(const float4*)&As_g[grow * 128 + kb + sk];
    float4 n4 = *(const float4*)&An_g[grow * 128 + kb + sk];
    As[sk + 0][sr] = a4.x; As[sk + 1][sr] = a4.y; As[sk + 2][sr] = a4.z; As[sk + 3][sr] = a4.w;
    An[sk + 0][sr] = n4.x; An[sk + 1][sr] = n4.y; An[sk + 2][sr] = n4.z; An[sk + 3][sr] = n4.w;
#pragma unroll
    for (int p = 0; p < 4; ++p) {
      int k = wk + p * 8;
      *(float4*)&Ws[k][wc] = *(const float4*)&Ws_g[(kb + k) * 128 + wc];
      *(float4*)&Wn[k][wc] = *(const float4*)&Wn_g[(kb + k) * 128 + wc];
    }
    __syncthreads();
#pragma unroll
    for (int k = 0; k < 32; ++k) {
      float4 a  = *(const float4*)&As[k][r0];
      float4 an = *(const float4*)&An[k][r0];
      float4 wv = *(const float4*)&Ws[k][c0];
      float4 wn = *(const float4*)&Wn[k][c0];
      float av[4]  = {a.x, a.y, a.z, a.w};
      float anv[4] = {an.x, an.y, an.z, an.w};
      float wvv[4] = {wv.x, wv.y, wv.z, wv.w};
      float wnv[4] = {wn.x, wn.y, wn.z, wn.w};
#pragma unroll
      for (int i = 0; i < 4; ++i)
#pragma unroll
        for (int j = 0; j < 4; ++j)
          acc[i][j] += av[i] * wvv[j] + anv[i] * wnv[j];
    }
    __syncthreads();
  }

  float bv[4] = {bias[c0], bias[c0 + 1], bias[c0 + 2], bias[c0 + 3]};
#pragma unroll
  for (int i = 0; i < 4; ++i) {
    int row = rowBase + r0 + i;
    if (row < N) {
      float4 o;
      o.x = acc[i][0] + bv[0];
      o.y = acc[i][1] + bv[1];
      o.z = acc[i][2] + bv[2];
      o.w = acc[i][3] + bv[3];
      if (relu) {
        o.x = fmaxf(o.x, 0.f); o.y = fmaxf(o.y, 0.f);
        o.z = fmaxf(o.z, 0.f); o.w = fmaxf(o.w, 0.f);
      }
      *(float4*)&Out[row * 128 + c0] = o;
    }
  }
}

// ---------------- final FC: [N,128] @ [128,47] + b ----------------
// block = 192 threads = 4 row-groups x 48 cols (col 47 idle), 32 rows/block.

__global__ __launch_bounds__(192) void fc_kernel(const float* __restrict__ H,
                                                 const float* __restrict__ Wg,
                                                 const float* __restrict__ bg,
                                                 float* __restrict__ Out, int N) {
  __shared__ float Hs[32 * 128];
  __shared__ float Wsh[128 * 47];
  int tid = threadIdx.x;
  int rowBase = blockIdx.x * 32;
  for (int i = tid; i < 128 * 47; i += 192) Wsh[i] = Wg[i];
  for (int i4 = tid; i4 < 1024; i4 += 192) {
    int r = i4 >> 5;
    int k4 = (i4 & 31) << 2;
    int grow = rowBase + r;
    if (grow >= N) grow = N - 1;
    *(float4*)&Hs[r * 128 + k4] = *(const float4*)&H[grow * 128 + k4];
  }
  __syncthreads();
  int c = tid % 48;
  int rg = tid / 48;  // 0..3
  float acc[8] = {0.f, 0.f, 0.f, 0.f, 0.f, 0.f, 0.f, 0.f};
  if (c < 47) {
#pragma unroll 4
    for (int k = 0; k < 128; ++k) {
      float wv = Wsh[k * 47 + c];
#pragma unroll
      for (int i = 0; i < 8; ++i)
        acc[i] += Hs[(rg * 8 + i) * 128 + k] * wv;
    }
    float bb = bg[c];
#pragma unroll
    for (int i = 0; i < 8; ++i) {
      int row = rowBase + rg * 8 + i;
      if (row < N) Out[row * 47 + c] = acc[i] + bb;
    }
  }
}

// ---------------- launch ----------------

extern "C" void kernel_launch(void* const* d_in, const int* in_sizes, int n_in,
                              void* d_out, int out_size, void* d_ws, size_t ws_size,
                              hipStream_t stream) {
  const float* feat    = (const float*)d_in[0];
  const int*   src     = (const int*)d_in[1];
  const int*   dst     = (const int*)d_in[2];
  const float* Wself0  = (const float*)d_in[3];
  const float* Wneigh0 = (const float*)d_in[4];
  const float* b0      = (const float*)d_in[5];
  const float* Wself1  = (const float*)d_in[6];
  const float* Wneigh1 = (const float*)d_in[7];
  const float* b1      = (const float*)d_in[8];
  const float* Wfc     = (const float*)d_in[9];
  const float* bfc     = (const float*)d_in[10];
  float* out = (float*)d_out;

  char* w = (char*)d_ws;
  int*   offs = (int*)(w);                 // (N+1) ints
  int*   cnt  = (int*)(w + 262144);        // N ints (counts -> cursors)
  int*   csr  = (int*)(w + 524288);        // E ints
  float* hn   = (float*)(w + 6924288);     // N*128 f32 (h_neigh; layer-1 h written in-place)
  float* h0   = (float*)(w + 32524288);    // N*128 f32

  const int E = NE, N = NN;

  hipMemsetAsync(cnt, 0, N * sizeof(int), stream);
  count_kernel<<<(E + 255) / 256, 256, 0, stream>>>(dst, cnt, E);
  scan_kernel<<<1, 1024, 0, stream>>>(cnt, offs, N);
  fill_kernel<<<(E + 255) / 256, 256, 0, stream>>>(src, dst, cnt, csr, E);

  const int gblocks = (N + 31) / 32;

  agg_kernel<<<N, 128, 0, stream>>>(feat, csr, offs, hn);
  gemm_sage<<<gblocks, 256, 0, stream>>>(feat, hn, Wself0, Wneigh0, b0, h0, N, 1);
  agg_kernel<<<N, 128, 0, stream>>>(h0, csr, offs, hn);
  gemm_sage<<<gblocks, 256, 0, stream>>>(h0, hn, Wself1, Wneigh1, b1, hn, N, 1);  // in-place
  fc_kernel<<<gblocks, 192, 0, stream>>>(hn, Wfc, bfc, out, N);
}

// Round 2
// 639.291 us; speedup vs baseline: 1.1772x; 1.1772x over previous
//
#include <hip/hip_runtime.h>

#define NN 50000
#define NE 1600000

// ---------------- CSR build ----------------

__global__ __launch_bounds__(256) void count_kernel(const int* __restrict__ dst,
                                                    int* __restrict__ cnt, int E) {
  int e = blockIdx.x * 256 + threadIdx.x;
  if (e < E) atomicAdd(&cnt[dst[e]], 1);
}

// single-block scan: reads counts from cnt, writes offs[0..n] (inclusive shifted)
// and rewrites cnt[i] = exclusive prefix (cursor for fill).
__global__ __launch_bounds__(1024) void scan_kernel(int* __restrict__ cnt,
                                                    int* __restrict__ offs, int n) {
  __shared__ int wsum[16];
  __shared__ int carry_s;
  int tid = threadIdx.x;
  int lane = tid & 63, wid = tid >> 6;
  if (tid == 0) { carry_s = 0; offs[0] = 0; }
  __syncthreads();
  for (int base = 0; base < n; base += 1024) {
    int i = base + tid;
    int v = (i < n) ? cnt[i] : 0;
    int x = v;
#pragma unroll
    for (int d = 1; d < 64; d <<= 1) {
      int y = __shfl_up(x, d, 64);
      if (lane >= d) x += y;
    }
    if (lane == 63) wsum[wid] = x;
    __syncthreads();
    if (tid < 16) {
      int s = wsum[tid];
#pragma unroll
      for (int d = 1; d < 16; d <<= 1) {
        int y = __shfl_up(s, d, 16);
        if (tid >= d) s += y;
      }
      wsum[tid] = s;
    }
    __syncthreads();
    int wave_off = (wid > 0) ? wsum[wid - 1] : 0;
    int c = carry_s;
    int incl = c + wave_off + x;
    if (i < n) {
      offs[i + 1] = incl;
      cnt[i] = incl - v;  // exclusive prefix -> cursor
    }
    __syncthreads();               // everyone read carry_s before update
    if (tid == 1023) carry_s = incl;
    __syncthreads();
  }
}

__global__ __launch_bounds__(256) void fill_kernel(const int* __restrict__ src,
                                                   const int* __restrict__ dst,
                                                   int* __restrict__ cur,
                                                   int* __restrict__ csr, int E) {
  int e = blockIdx.x * 256 + threadIdx.x;
  if (e < E) {
    int p = atomicAdd(&cur[dst[e]], 1);
    csr[p] = src[e];
  }
}

// ---------------- segment mean (gather form, no float atomics) ----------------
// 256 threads = 8 nodes/block; 32 lanes per node, float4 per lane (128 dims).
// Neighbor loop unrolled x8 with 2 partial accumulators -> 8 outstanding
// 16B loads per lane per window (latency hiding).

__global__ __launch_bounds__(256) void agg_kernel(const float* __restrict__ X,
                                                  const int* __restrict__ csr,
                                                  const int* __restrict__ offs,
                                                  float* __restrict__ out, int N) {
  const float4* __restrict__ X4 = (const float4*)X;
  int tid = threadIdx.x;
  int slot = tid >> 5;           // 0..7
  int lane = tid & 31;           // 32 lanes -> 128 dims via float4
  int n = blockIdx.x * 8 + slot;
  if (n >= N) return;
  int s = offs[n], e = offs[n + 1];

  float4 accA = make_float4(0.f, 0.f, 0.f, 0.f);
  float4 accB = make_float4(0.f, 0.f, 0.f, 0.f);

  int j = s;
  for (; j + 8 <= e; j += 8) {
    int i0 = csr[j + 0], i1 = csr[j + 1], i2 = csr[j + 2], i3 = csr[j + 3];
    int i4 = csr[j + 4], i5 = csr[j + 5], i6 = csr[j + 6], i7 = csr[j + 7];
    float4 a0 = X4[i0 * 32 + lane];
    float4 a1 = X4[i1 * 32 + lane];
    float4 a2 = X4[i2 * 32 + lane];
    float4 a3 = X4[i3 * 32 + lane];
    float4 a4 = X4[i4 * 32 + lane];
    float4 a5 = X4[i5 * 32 + lane];
    float4 a6 = X4[i6 * 32 + lane];
    float4 a7 = X4[i7 * 32 + lane];
    accA.x += (a0.x + a1.x) + (a2.x + a3.x);
    accA.y += (a0.y + a1.y) + (a2.y + a3.y);
    accA.z += (a0.z + a1.z) + (a2.z + a3.z);
    accA.w += (a0.w + a1.w) + (a2.w + a3.w);
    accB.x += (a4.x + a5.x) + (a6.x + a7.x);
    accB.y += (a4.y + a5.y) + (a6.y + a7.y);
    accB.z += (a4.z + a5.z) + (a6.z + a7.z);
    accB.w += (a4.w + a5.w) + (a6.w + a7.w);
  }
  for (; j < e; ++j) {
    int i0 = csr[j];
    float4 a0 = X4[i0 * 32 + lane];
    accA.x += a0.x; accA.y += a0.y; accA.z += a0.z; accA.w += a0.w;
  }

  float inv = 1.0f / fmaxf((float)(e - s), 1.0f);
  float4 o;
  o.x = (accA.x + accB.x) * inv;
  o.y = (accA.y + accB.y) * inv;
  o.z = (accA.z + accB.z) * inv;
  o.w = (accA.w + accB.w) * inv;
  ((float4*)out)[n * 32 + lane] = o;
}

// ---------------- fused dual-GEMM: Out = act(Aself*Ws + Aneigh*Wn + b) ----------------
// block = 256 threads, 32 rows x 128 cols per block, K tiled by 32.
// In-place safe when Out aliases Aneigh (one block owns its 32-row stripe,
// all reads of those rows precede the epilogue writes; no column tiling).

__global__ __launch_bounds__(256) void gemm_sage(
    const float* __restrict__ As_g, const float* __restrict__ An_g,
    const float* __restrict__ Ws_g, const float* __restrict__ Wn_g,
    const float* __restrict__ bias, float* __restrict__ Out,
    int N, int relu) {
  __shared__ float As[32][36];   // transposed A tile [k][r], +4 pad (16B-aligned rows)
  __shared__ float An[32][36];
  __shared__ float Ws[32][128];
  __shared__ float Wn[32][128];
  int tid = threadIdx.x;
  int r0 = (tid >> 5) << 2;      // 8 row-groups * 4
  int c0 = (tid & 31) << 2;      // 32 col-groups * 4
  int rowBase = blockIdx.x * 32;

  float acc[4][4] = {{0.f}};

  int sr = tid >> 3;             // stage: A row 0..31
  int sk = (tid & 7) << 2;       // stage: A k-offset 0,4..28
  int grow = rowBase + sr;
  if (grow >= N) grow = N - 1;   // clamp stays inside this block's stripe
  int wc = (tid & 31) << 2;      // stage: W col*4
  int wk = tid >> 5;             // stage: W k-row 0..7

  for (int kb = 0; kb < 128; kb += 32) {
    float4 a4 = *(const float4*)&As_g[grow * 128 + kb + sk];
    float4 n4 = *(const float4*)&An_g[grow * 128 + kb + sk];
    As[sk + 0][sr] = a4.x; As[sk + 1][sr] = a4.y; As[sk + 2][sr] = a4.z; As[sk + 3][sr] = a4.w;
    An[sk + 0][sr] = n4.x; An[sk + 1][sr] = n4.y; An[sk + 2][sr] = n4.z; An[sk + 3][sr] = n4.w;
#pragma unroll
    for (int p = 0; p < 4; ++p) {
      int k = wk + p * 8;
      *(float4*)&Ws[k][wc] = *(const float4*)&Ws_g[(kb + k) * 128 + wc];
      *(float4*)&Wn[k][wc] = *(const float4*)&Wn_g[(kb + k) * 128 + wc];
    }
    __syncthreads();
#pragma unroll
    for (int k = 0; k < 32; ++k) {
      float4 a  = *(const float4*)&As[k][r0];
      float4 an = *(const float4*)&An[k][r0];
      float4 wv = *(const float4*)&Ws[k][c0];
      float4 wn = *(const float4*)&Wn[k][c0];
      float av[4]  = {a.x, a.y, a.z, a.w};
      float anv[4] = {an.x, an.y, an.z, an.w};
      float wvv[4] = {wv.x, wv.y, wv.z, wv.w};
      float wnv[4] = {wn.x, wn.y, wn.z, wn.w};
#pragma unroll
      for (int i = 0; i < 4; ++i)
#pragma unroll
        for (int j = 0; j < 4; ++j)
          acc[i][j] += av[i] * wvv[j] + anv[i] * wnv[j];
    }
    __syncthreads();
  }

  float bv[4] = {bias[c0], bias[c0 + 1], bias[c0 + 2], bias[c0 + 3]};
#pragma unroll
  for (int i = 0; i < 4; ++i) {
    int row = rowBase + r0 + i;
    if (row < N) {
      float4 o;
      o.x = acc[i][0] + bv[0];
      o.y = acc[i][1] + bv[1];
      o.z = acc[i][2] + bv[2];
      o.w = acc[i][3] + bv[3];
      if (relu) {
        o.x = fmaxf(o.x, 0.f); o.y = fmaxf(o.y, 0.f);
        o.z = fmaxf(o.z, 0.f); o.w = fmaxf(o.w, 0.f);
      }
      *(float4*)&Out[row * 128 + c0] = o;
    }
  }
}

// ---------------- final FC: [N,128] @ [128,47] + b ----------------
// block = 192 threads = 4 row-groups x 48 cols (col 47 idle), 32 rows/block.

__global__ __launch_bounds__(192) void fc_kernel(const float* __restrict__ H,
                                                 const float* __restrict__ Wg,
                                                 const float* __restrict__ bg,
                                                 float* __restrict__ Out, int N) {
  __shared__ float Hs[32 * 128];
  __shared__ float Wsh[128 * 47];
  int tid = threadIdx.x;
  int rowBase = blockIdx.x * 32;
  for (int i = tid; i < 128 * 47; i += 192) Wsh[i] = Wg[i];
  for (int i4 = tid; i4 < 1024; i4 += 192) {
    int r = i4 >> 5;
    int k4 = (i4 & 31) << 2;
    int grow = rowBase + r;
    if (grow >= N) grow = N - 1;
    *(float4*)&Hs[r * 128 + k4] = *(const float4*)&H[grow * 128 + k4];
  }
  __syncthreads();
  int c = tid % 48;
  int rg = tid / 48;  // 0..3
  float acc[8] = {0.f, 0.f, 0.f, 0.f, 0.f, 0.f, 0.f, 0.f};
  if (c < 47) {
#pragma unroll 4
    for (int k = 0; k < 128; ++k) {
      float wv = Wsh[k * 47 + c];
#pragma unroll
      for (int i = 0; i < 8; ++i)
        acc[i] += Hs[(rg * 8 + i) * 128 + k] * wv;
    }
    float bb = bg[c];
#pragma unroll
    for (int i = 0; i < 8; ++i) {
      int row = rowBase + rg * 8 + i;
      if (row < N) Out[row * 47 + c] = acc[i] + bb;
    }
  }
}

// ---------------- launch ----------------

extern "C" void kernel_launch(void* const* d_in, const int* in_sizes, int n_in,
                              void* d_out, int out_size, void* d_ws, size_t ws_size,
                              hipStream_t stream) {
  const float* feat    = (const float*)d_in[0];
  const int*   src     = (const int*)d_in[1];
  const int*   dst     = (const int*)d_in[2];
  const float* Wself0  = (const float*)d_in[3];
  const float* Wneigh0 = (const float*)d_in[4];
  const float* b0      = (const float*)d_in[5];
  const float* Wself1  = (const float*)d_in[6];
  const float* Wneigh1 = (const float*)d_in[7];
  const float* b1      = (const float*)d_in[8];
  const float* Wfc     = (const float*)d_in[9];
  const float* bfc     = (const float*)d_in[10];
  float* out = (float*)d_out;

  char* w = (char*)d_ws;
  int*   offs = (int*)(w);                 // (N+1) ints
  int*   cnt  = (int*)(w + 262144);        // N ints (counts -> cursors)
  int*   csr  = (int*)(w + 524288);        // E ints
  float* hn   = (float*)(w + 6924288);     // N*128 f32 (h_neigh; layer-1 h written in-place)
  float* h0   = (float*)(w + 32524288);    // N*128 f32

  const int E = NE, N = NN;

  hipMemsetAsync(cnt, 0, N * sizeof(int), stream);
  count_kernel<<<(E + 255) / 256, 256, 0, stream>>>(dst, cnt, E);
  scan_kernel<<<1, 1024, 0, stream>>>(cnt, offs, N);
  fill_kernel<<<(E + 255) / 256, 256, 0, stream>>>(src, dst, cnt, csr, E);

  const int gblocks = (N + 31) / 32;

  agg_kernel<<<(N + 7) / 8, 256, 0, stream>>>(feat, csr, offs, hn, N);
  gemm_sage<<<gblocks, 256, 0, stream>>>(feat, hn, Wself0, Wneigh0, b0, h0, N, 1);
  agg_kernel<<<(N + 7) / 8, 256, 0, stream>>>(h0, csr, offs, hn, N);
  gemm_sage<<<gblocks, 256, 0, stream>>>(h0, hn, Wself1, Wneigh1, b1, hn, N, 1);  // in-place
  fc_kernel<<<gblocks, 192, 0, stream>>>(hn, Wfc, bfc, out, N);
}